// Round 8
// baseline (413.800 us; speedup 1.0000x reference)
//
#include <hip/hip_runtime.h>
#include <hip/hip_bf16.h>

#define Tt 2048
#define Dd 2048
#define Ff 512
#define Ee 16
#define NE 17                    // 16 routed experts + 1 shared
#define MAXROWS 12288            // 80 routed tiles*128 + 16 shared tiles*128
#define MAXTILES 96

typedef __attribute__((ext_vector_type(8))) short short8;
typedef __attribute__((ext_vector_type(8))) unsigned short ushort8v;
typedef __attribute__((ext_vector_type(4))) float floatx4;

#define AS1 __attribute__((address_space(1)))
#define AS3 __attribute__((address_space(3)))

__device__ __forceinline__ unsigned short f2bf(float f) {
    union { float f; unsigned u; } v; v.f = f;
    unsigned r = v.u + 0x7FFFu + ((v.u >> 16) & 1u);   // RNE
    return (unsigned short)(r >> 16);
}
__device__ __forceinline__ float bf2f(unsigned short h) {
    union { unsigned u; float f; } v; v.u = ((unsigned)h) << 16;
    return v.f;
}

__device__ __forceinline__ void gld16(const unsigned short* g, unsigned short* l) {
    __builtin_amdgcn_global_load_lds((const AS1 void*)g, (AS3 void*)l, 16, 0, 0);
}

// ---------------- split-cast x -> bf16 hi + bf16 lo ----------------
__global__ void splitcast_x(const float* __restrict__ x, unsigned short* __restrict__ xh,
                            unsigned short* __restrict__ xl) {
    int i = (blockIdx.x * 256 + threadIdx.x) * 8;
    float v[8];
    *(floatx4*)&v[0] = *(const floatx4*)(x + i);
    *(floatx4*)&v[4] = *(const floatx4*)(x + i + 4);
    ushort8v h, l;
#pragma unroll
    for (int j = 0; j < 8; j++) {
        unsigned short hb = f2bf(v[j]);
        h[j] = hb;
        l[j] = f2bf(v[j] - bf2f(hb));
    }
    *(ushort8v*)(xh + i) = h;
    *(ushort8v*)(xl + i) = l;
}

// ---------------- split gate weights into gB[2][32][2048] (hi,lo), rows 17..31 zero ----------------
__global__ void splitg_kernel(const float* __restrict__ gw, const float* __restrict__ sgw,
                              unsigned short* __restrict__ gB) {
    int z = blockIdx.x;                // 0..31
    int i = threadIdx.x * 8;
    ushort8v h = {0,0,0,0,0,0,0,0}, l = {0,0,0,0,0,0,0,0};
    if (z < NE) {
        const float* src = (z < Ee) ? (gw + (size_t)z * Dd) : sgw;
        float v[8];
        *(floatx4*)&v[0] = *(const floatx4*)(src + i);
        *(floatx4*)&v[4] = *(const floatx4*)(src + i + 4);
#pragma unroll
        for (int j = 0; j < 8; j++) {
            unsigned short hb = f2bf(v[j]);
            h[j] = hb;
            l[j] = f2bf(v[j] - bf2f(hb));
        }
    }
    *(ushort8v*)(gB + (size_t)z * Dd + i) = h;
    *(ushort8v*)(gB + 32 * Dd + (size_t)z * Dd + i) = l;
}

// ---------------- logits GEMM: part[kb][t][n] = sum_k x*gw (hi/lo compensated) ----------------
__global__ __launch_bounds__(256) void logits_kernel(
    const unsigned short* __restrict__ xh, const unsigned short* __restrict__ xl,
    const unsigned short* __restrict__ gB, float* __restrict__ part) {
    __shared__ unsigned short sAh[128 * 32];
    __shared__ unsigned short sAl[128 * 32];
    __shared__ unsigned short sB[2048];     // [0..1023] hi 32x32, [1024..2047] lo 32x32
    const int m0 = blockIdx.x * 128;
    const int kb = blockIdx.y;
    const int k00 = kb * 256;
    const int tid = threadIdx.x;
    const int lane = tid & 63, wv = tid >> 6;
    const int lr = lane & 15, quad = lane >> 4;

    const int l0 = tid * 8;
    const int r0 = l0 >> 5, c0 = l0 & 31;
    const int l1 = l0 + 2048;
    const int r1 = r0 + 64;
    const int br = (tid >> 2) & 31, bc = (tid & 3) * 8;
    const unsigned short* bsrc = gB + ((tid >= 128) ? 32 * Dd : 0) + (size_t)br * Dd + bc;

    floatx4 acc[2][2];
#pragma unroll
    for (int i = 0; i < 2; i++)
#pragma unroll
        for (int j = 0; j < 2; j++) acc[i][j] = (floatx4){0.f, 0.f, 0.f, 0.f};

    for (int kk = 0; kk < 256; kk += 32) {
        __syncthreads();
        gld16(xh + (size_t)(m0 + r0) * Dd + k00 + kk + c0, &sAh[l0]);
        gld16(xh + (size_t)(m0 + r1) * Dd + k00 + kk + c0, &sAh[l1]);
        gld16(xl + (size_t)(m0 + r0) * Dd + k00 + kk + c0, &sAl[l0]);
        gld16(xl + (size_t)(m0 + r1) * Dd + k00 + kk + c0, &sAl[l1]);
        gld16(bsrc + k00 + kk, &sB[l0 & 2047]);
        __syncthreads();
#pragma unroll
        for (int mi = 0; mi < 2; mi++) {
            const int ar = wv * 32 + mi * 16 + lr;
            short8 ah = *(const short8*)&sAh[ar * 32 + quad * 8];
            short8 al = *(const short8*)&sAl[ar * 32 + quad * 8];
#pragma unroll
            for (int nj = 0; nj < 2; nj++) {
                short8 bh = *(const short8*)&sB[(nj * 16 + lr) * 32 + quad * 8];
                short8 bl = *(const short8*)&sB[1024 + (nj * 16 + lr) * 32 + quad * 8];
                acc[mi][nj] = __builtin_amdgcn_mfma_f32_16x16x32_bf16(ah, bh, acc[mi][nj], 0, 0, 0);
                acc[mi][nj] = __builtin_amdgcn_mfma_f32_16x16x32_bf16(ah, bl, acc[mi][nj], 0, 0, 0);
                acc[mi][nj] = __builtin_amdgcn_mfma_f32_16x16x32_bf16(al, bh, acc[mi][nj], 0, 0, 0);
            }
        }
    }
#pragma unroll
    for (int mi = 0; mi < 2; mi++)
#pragma unroll
        for (int r = 0; r < 4; r++) {
            const int t = m0 + wv * 32 + mi * 16 + quad * 4 + r;
#pragma unroll
            for (int nj = 0; nj < 2; nj++)
                part[((size_t)kb * Tt + t) * 32 + nj * 16 + lr] = acc[mi][nj][r];
        }
}

// ---------------- topk: reduce split-K partials, softmax, top4, shared gate ----------------
__global__ void topk_kernel(const float* __restrict__ part, float* __restrict__ comb,
                            int* __restrict__ selids, int* __restrict__ counts) {
    const int t = blockIdx.x * 64 + threadIdx.x;
    float lg[20];
#pragma unroll
    for (int j = 0; j < 20; j++) lg[j] = 0.f;
#pragma unroll
    for (int kb = 0; kb < 8; kb++) {
        const float* p = part + ((size_t)kb * Tt + t) * 32;
#pragma unroll
        for (int q = 0; q < 5; q++) {
            floatx4 a = *(const floatx4*)(p + q * 4);
            lg[q * 4 + 0] += a.x; lg[q * 4 + 1] += a.y;
            lg[q * 4 + 2] += a.z; lg[q * 4 + 3] += a.w;
        }
    }
    float mx = lg[0];
    for (int e = 1; e < Ee; e++) mx = fmaxf(mx, lg[e]);
    float p[Ee]; float sum = 0.f;
    for (int e = 0; e < Ee; e++) { p[e] = __expf(lg[e] - mx); sum += p[e]; }
    float inv = 1.f / sum;
    for (int e = 0; e < Ee; e++) p[e] *= inv;
    bool sel[Ee];
    for (int e = 0; e < Ee; e++) sel[e] = false;
    int ids[4];
    float ssum = 0.f;
    for (int k = 0; k < 4; k++) {
        int bi = 0; float bv = -1.f;
        for (int e = 0; e < Ee; e++)
            if (!sel[e] && p[e] > bv) { bv = p[e]; bi = e; }
        sel[bi] = true; ids[k] = bi; ssum += bv;
    }
    float rinv = 1.f / ssum;
    for (int e = 0; e < Ee; e++) comb[t * NE + e] = sel[e] ? p[e] * rinv : 0.f;
    comb[t * NE + Ee] = 1.f / (1.f + __expf(-lg[16]));
#pragma unroll
    for (int k = 0; k < 4; k++) {
        selids[t * 4 + k] = ids[k];
        atomicAdd(&counts[ids[k]], 1);
    }
}

// ---------------- offsets: tile-padded exclusive scan + block table ----------------
__global__ void offsets_kernel(const int* __restrict__ counts, int* __restrict__ off,
                               int* __restrict__ cursor, int* __restrict__ blocktab,
                               int* __restrict__ meta) {
    int acc = 0, nt = 0;
    for (int e = 0; e < NE; e++) {
        int c = (e < Ee) ? counts[e] : Tt;
        off[e] = acc;
        if (e < Ee) cursor[e] = 0;
        int tiles = (c + 127) >> 7;
        for (int tl = 0; tl < tiles; tl++) blocktab[nt++] = (e << 20) | (acc + tl * 128);
        acc += tiles << 7;
    }
    meta[0] = nt;
}

// ---------------- scatter: rowmap (pos -> token) + tokpos (token -> its 5 positions) ----------------
__global__ void scatter_kernel(const int* __restrict__ selids, const int* __restrict__ off,
                               int* __restrict__ cursor, int* __restrict__ rowmap,
                               int* __restrict__ tokpos) {
    int t = blockIdx.x * 256 + threadIdx.x;
    if (t >= Tt) return;
#pragma unroll
    for (int k = 0; k < 4; k++) {
        int e = selids[t * 4 + k];
        int r = atomicAdd(&cursor[e], 1);
        int pos = off[e] + r;
        rowmap[pos] = t;
        tokpos[t * 8 + k] = pos;
    }
    int sp = off[Ee] + t;
    rowmap[sp] = t;            // shared expert: identity
    tokpos[t * 8 + 4] = sp;
}

// ---------------- GEMM1: Hp[pos][f] = comb * silu(x@Wg_e) * (x@Wu_e) ----------------
// 128x64 tile, DOUBLE-BUFFERED LDS (A via gld16, B via register transpose).
// One barrier per K-iter; all loads for iter i+1 issued at top of iter i so the
// barrier's vmcnt(0) drain finds them ~complete. Swizzled B layout from r7.
__global__ __launch_bounds__(256, 2) void gemm1_kernel(
    const unsigned short* __restrict__ xb,
    const float* __restrict__ Wg, const float* __restrict__ sWg,
    const float* __restrict__ Wu, const float* __restrict__ sWu,
    const float* __restrict__ comb,
    const int* __restrict__ rowmap,
    const int* __restrict__ blocktab,
    const int* __restrict__ meta,
    unsigned short* __restrict__ Hp)
{
    if ((int)blockIdx.y >= meta[0]) return;
    __shared__ unsigned short sA[2][128 * 32];
    __shared__ unsigned short sB2[2][2][64 * 40];   // [buf][plane: 0=G,1=U]
    const int info = blocktab[blockIdx.y];
    const int e  = info >> 20;
    const int m0 = info & 0xFFFFF;
    const int n0 = blockIdx.x * 64;
    const int tid = threadIdx.x;
    const int lane = tid & 63, wv = tid >> 6;
    const int wm = (wv >> 1) * 64, wn = (wv & 1) * 32;
    const int lr = lane & 15, quad = lane >> 4;

    const float* Gsrc = (e < Ee) ? (Wg + (size_t)e * Dd * Ff) : sWg;
    const float* Usrc = (e < Ee) ? (Wu + (size_t)e * Dd * Ff) : sWu;
    const int sx = tid & 15, sy = (tid >> 4) & 7, plane = tid >> 7;
    const float* psrc = (plane ? Usrc : Gsrc) + (size_t)(sy * 4) * Ff + n0 + sx * 4;
    const int sOff = (sx * 4) * 40 + ((sy ^ ((sx & 3) * 2)) * 4);
    const int koff = ((quad * 2) ^ ((lr >> 2) * 2)) * 4;

    const int l0 = tid * 8;
    const int r0 = l0 >> 5, c0 = l0 & 31;
    const int l1 = l0 + 2048;
    const int r1 = r0 + 64;
    const int tk0 = rowmap[m0 + r0];
    const int tk1 = rowmap[m0 + r1];
    const unsigned short* a0 = xb + (size_t)(tk0 < 0 ? 0 : tk0) * Dd + c0;
    const unsigned short* a1 = xb + (size_t)(tk1 < 0 ? 0 : tk1) * Dd + c0;

    // prologue: stage k-tile 0 into buf0, prefetch k-tile 1 into regs
    floatx4 nxt[4];
    {
        floatx4 cur[4];
#pragma unroll
        for (int i = 0; i < 4; i++) cur[i] = *(const floatx4*)(psrc + (size_t)i * Ff);
        unsigned short* d = &sB2[0][plane][sOff];
#pragma unroll
        for (int jj = 0; jj < 4; jj++) {
            ushort4 w;
            w.x = f2bf(cur[0][jj]); w.y = f2bf(cur[1][jj]);
            w.z = f2bf(cur[2][jj]); w.w = f2bf(cur[3][jj]);
            *(ushort4*)&d[jj * 40] = w;
        }
    }
    gld16(a0, &sA[0][l0]);
    gld16(a1, &sA[0][l1]);
#pragma unroll
    for (int i = 0; i < 4; i++) nxt[i] = *(const floatx4*)(psrc + (size_t)32 * Ff + (size_t)i * Ff);

    floatx4 accg[4][2], accu[4][2];
#pragma unroll
    for (int i = 0; i < 4; i++)
#pragma unroll
        for (int j = 0; j < 2; j++) {
            accg[i][j] = (floatx4){0.f, 0.f, 0.f, 0.f};
            accu[i][j] = (floatx4){0.f, 0.f, 0.f, 0.f};
        }

    for (int k0 = 0; k0 < Dd; k0 += 32) {
        const int buf = (k0 >> 5) & 1;
        __syncthreads();
        if (k0 + 32 < Dd) {
            gld16(a0 + k0 + 32, &sA[buf ^ 1][l0]);
            gld16(a1 + k0 + 32, &sA[buf ^ 1][l1]);
        }
        floatx4 nn[4];
        if (k0 + 64 < Dd) {
            const float* np = psrc + (size_t)(k0 + 64) * Ff;
#pragma unroll
            for (int i = 0; i < 4; i++) nn[i] = *(const floatx4*)(np + (size_t)i * Ff);
        }
        short8 af[4];
#pragma unroll
        for (int i = 0; i < 4; i++)
            af[i] = *(const short8*)&sA[buf][(wm + i * 16 + lr) * 32 + quad * 8];
#pragma unroll
        for (int j = 0; j < 2; j++) {
            short8 bg = *(const short8*)&sB2[buf][0][(wn + j * 16 + lr) * 40 + koff];
            short8 bu = *(const short8*)&sB2[buf][1][(wn + j * 16 + lr) * 40 + koff];
#pragma unroll
            for (int i = 0; i < 4; i++) {
                accg[i][j] = __builtin_amdgcn_mfma_f32_16x16x32_bf16(af[i], bg, accg[i][j], 0, 0, 0);
                accu[i][j] = __builtin_amdgcn_mfma_f32_16x16x32_bf16(af[i], bu, accu[i][j], 0, 0, 0);
            }
        }
        if (k0 + 32 < Dd) {
            unsigned short* d = &sB2[buf ^ 1][plane][sOff];
#pragma unroll
            for (int jj = 0; jj < 4; jj++) {
                ushort4 w;
                w.x = f2bf(nxt[0][jj]); w.y = f2bf(nxt[1][jj]);
                w.z = f2bf(nxt[2][jj]); w.w = f2bf(nxt[3][jj]);
                *(ushort4*)&d[jj * 40] = w;
            }
#pragma unroll
            for (int i = 0; i < 4; i++) nxt[i] = nn[i];
        }
    }
#pragma unroll
    for (int i = 0; i < 4; i++) {
#pragma unroll
        for (int r = 0; r < 4; r++) {
            const int pos = m0 + wm + i * 16 + quad * 4 + r;
            const int tok = rowmap[pos];
            const float wc = (tok >= 0) ? comb[tok * NE + e] : 0.f;
#pragma unroll
            for (int j = 0; j < 2; j++) {
                const float g = accg[i][j][r];
                const float u = accu[i][j][r];
                const float h = (g / (1.f + __expf(-g))) * u * wc;
                Hp[(size_t)pos * Ff + (n0 + wn + j * 16 + lr)] = f2bf(h);
            }
        }
    }
}

// ---------------- GEMM2: Op[pos] = Hp[pos] @ Wd_e (dbuf, native fp32 Wd, bf16 out) ----------------
__global__ __launch_bounds__(256, 2) void gemm2_kernel(
    const unsigned short* __restrict__ Hp,
    const float* __restrict__ Wd, const float* __restrict__ sWd,   // native [F][D]
    const int* __restrict__ blocktab,
    const int* __restrict__ meta,
    unsigned short* __restrict__ Op)          // [MAXROWS][D] bf16 packed
{
    if ((int)blockIdx.y >= meta[0]) return;
    __shared__ unsigned short sA[2][128 * 32];      // 8192 ushorts (also epilogue staging)
    __shared__ unsigned short sB[2][128 * 40];
    const int info = blocktab[blockIdx.y];
    const int e  = info >> 20;
    const int m0 = info & 0xFFFFF;
    const int n0 = blockIdx.x * 128;
    const int tid = threadIdx.x;
    const int lane = tid & 63, wv = tid >> 6;
    const int wm = (wv >> 1) * 64, wn = (wv & 1) * 64;
    const int lr = lane & 15, quad = lane >> 4;

    const unsigned short* Ab = Hp + (size_t)m0 * Ff;
    const float* Dsrc = (e < Ee) ? (Wd + (size_t)e * Ff * Dd) : sWd;
    const int sx = tid & 15, sy = (tid >> 4) & 7, plane = tid >> 7;
    const float* psrc = Dsrc + (size_t)(sy * 4) * Dd + n0 + plane * 64 + sx * 4;
    const int sOff = (plane * 64 + sx * 4) * 40 + ((sy ^ ((sx & 3) * 2)) * 4);
    const int koff = ((quad * 2) ^ ((lr >> 2) * 2)) * 4;

    const int l0 = tid * 8;
    const int r0 = l0 >> 5, c0 = l0 & 31;
    const int l1 = l0 + 2048;
    const int r1 = r0 + 64;

    // prologue
    floatx4 nxt[4];
    {
        floatx4 cur[4];
#pragma unroll
        for (int i = 0; i < 4; i++) cur[i] = *(const floatx4*)(psrc + (size_t)i * Dd);
        unsigned short* d = &sB[0][sOff];
#pragma unroll
        for (int jj = 0; jj < 4; jj++) {
            ushort4 w;
            w.x = f2bf(cur[0][jj]); w.y = f2bf(cur[1][jj]);
            w.z = f2bf(cur[2][jj]); w.w = f2bf(cur[3][jj]);
            *(ushort4*)&d[jj * 40] = w;
        }
    }
    gld16(Ab + (size_t)r0 * Ff + c0, &sA[0][l0]);
    gld16(Ab + (size_t)r1 * Ff + c0, &sA[0][l1]);
#pragma unroll
    for (int i = 0; i < 4; i++) nxt[i] = *(const floatx4*)(psrc + (size_t)32 * Dd + (size_t)i * Dd);

    floatx4 acc[4][4];
#pragma unroll
    for (int i = 0; i < 4; i++)
#pragma unroll
        for (int j = 0; j < 4; j++) acc[i][j] = (floatx4){0.f, 0.f, 0.f, 0.f};

    for (int k0 = 0; k0 < Ff; k0 += 32) {
        const int buf = (k0 >> 5) & 1;
        __syncthreads();
        if (k0 + 32 < Ff) {
            gld16(Ab + (size_t)r0 * Ff + k0 + 32 + c0, &sA[buf ^ 1][l0]);
            gld16(Ab + (size_t)r1 * Ff + k0 + 32 + c0, &sA[buf ^ 1][l1]);
        }
        floatx4 nn[4];
        if (k0 + 64 < Ff) {
            const float* np = psrc + (size_t)(k0 + 64) * Dd;
#pragma unroll
            for (int i = 0; i < 4; i++) nn[i] = *(const floatx4*)(np + (size_t)i * Dd);
        }
        short8 af[4];
#pragma unroll
        for (int i = 0; i < 4; i++)
            af[i] = *(const short8*)&sA[buf][(wm + i * 16 + lr) * 32 + quad * 8];
#pragma unroll
        for (int j = 0; j < 4; j++) {
            short8 bf = *(const short8*)&sB[buf][(wn + j * 16 + lr) * 40 + koff];
#pragma unroll
            for (int i = 0; i < 4; i++)
                acc[i][j] = __builtin_amdgcn_mfma_f32_16x16x32_bf16(af[i], bf, acc[i][j], 0, 0, 0);
        }
        if (k0 + 32 < Ff) {
            unsigned short* d = &sB[buf ^ 1][sOff];
#pragma unroll
            for (int jj = 0; jj < 4; jj++) {
                ushort4 w;
                w.x = f2bf(nxt[0][jj]); w.y = f2bf(nxt[1][jj]);
                w.z = f2bf(nxt[2][jj]); w.w = f2bf(nxt[3][jj]);
                *(ushort4*)&d[jj * 40] = w;
            }
#pragma unroll
            for (int i = 0; i < 4; i++) nxt[i] = nn[i];
        }
    }
    // epilogue: per-wave 64x64 bf16 tile staged through sA, coalesced ushort8 stores
    unsigned short* sOut = &sA[0][0] + wv * 2048;   // 4 KB per wave (32 rows x 64 cols)
    __syncthreads();                                // K-loop LDS reads done
#pragma unroll
    for (int h = 0; h < 2; h++) {
#pragma unroll
        for (int ii = 0; ii < 2; ii++) {
            const int i = h * 2 + ii;
#pragma unroll
            for (int r = 0; r < 4; r++) {
                const int lrow = ii * 16 + quad * 4 + r;
#pragma unroll
                for (int j = 0; j < 4; j++)
                    sOut[lrow * 64 + j * 16 + lr] = f2bf(acc[i][j][r]);
            }
        }
        __syncthreads();
        const int prow0 = m0 + wm + h * 32;
#pragma unroll
        for (int it = 0; it < 4; it++) {
            const int idx = it * 512 + lane * 8;
            const int row = idx >> 6, col = idx & 63;
            ushort8v vv = *(const ushort8v*)&sOut[row * 64 + col];
            *(ushort8v*)&Op[(size_t)(prow0 + row) * Dd + n0 + wn + col] = vv;
        }
        __syncthreads();
    }
}

// ---------------- reduce: out[t] = sum of the token's 5 packed Op rows ----------------
__global__ __launch_bounds__(256) void reduce_kernel(
    const unsigned short* __restrict__ Op, const int* __restrict__ tokpos,
    float* __restrict__ out)
{
    const int t = blockIdx.x;
    const int c = threadIdx.x * 8;
    int ps[5];
#pragma unroll
    for (int k = 0; k < 5; k++) ps[k] = tokpos[t * 8 + k];
    float s[8];
#pragma unroll
    for (int j = 0; j < 8; j++) s[j] = 0.f;
#pragma unroll
    for (int k = 0; k < 5; k++) {
        ushort8v v = *(const ushort8v*)&Op[(size_t)ps[k] * Dd + c];
#pragma unroll
        for (int j = 0; j < 8; j++) s[j] += bf2f(v[j]);
    }
    *(floatx4*)(out + (size_t)t * Dd + c) = *(floatx4*)&s[0];
    *(floatx4*)(out + (size_t)t * Dd + c + 4) = *(floatx4*)&s[4];
}

extern "C" void kernel_launch(void* const* d_in, const int* in_sizes, int n_in,
                              void* d_out, int out_size, void* d_ws, size_t ws_size,
                              hipStream_t stream) {
    const float* x   = (const float*)d_in[0];
    const float* gw  = (const float*)d_in[1];
    const float* Wg  = (const float*)d_in[2];
    const float* Wu  = (const float*)d_in[3];
    const float* Wd  = (const float*)d_in[4];
    const float* sWg = (const float*)d_in[5];
    const float* sWu = (const float*)d_in[6];
    const float* sWd = (const float*)d_in[7];
    const float* sgw = (const float*)d_in[8];
    float* out = (float*)d_out;

    // workspace layout (bytes)
    char* ws = (char*)d_ws;
    unsigned short* xb  = (unsigned short*)(ws);                 //  8,388,608  x bf16 hi [T][D]
    unsigned short* xl  = (unsigned short*)(ws + 8388608);       //  8,388,608  x bf16 lo [T][D]
    unsigned short* Op  = (unsigned short*)(ws + 16777216);      // 50,331,648  [MAXROWS][D]
    unsigned short* Hp  = (unsigned short*)(ws + 67108864);      // 12,582,912  packed [MAXROWS][F]
    float* part   = (float*)(ws + 79691776);                     //  2,097,152  [8][T][32]
    unsigned short* gB  = (unsigned short*)(ws + 81788928);      //    262,144  [2][32][D]
    float* comb   = (float*)(ws + 82051072);                     //    139,264  [T][NE]
    int* selids   = (int*)(ws + 82190336);                       //     32,768  [T][4]
    int* counts   = (int*)(ws + 82223104);                       //         64
    int* off      = (int*)(ws + 82223168);                       //        128
    int* cursor   = (int*)(ws + 82223296);                       //         64
    int* meta     = (int*)(ws + 82223360);                       //         64
    int* blocktab = (int*)(ws + 82223424);                       //        512
    int* rowmap   = (int*)(ws + 82223936);                       //     49,152 [MAXROWS]
    int* tokpos   = (int*)(ws + 82273088);                       //     65,536 [T][8]

    splitcast_x<<<Tt * Dd / 2048, 256, 0, stream>>>(x, xb, xl);
    splitg_kernel<<<32, 256, 0, stream>>>(gw, sgw, gB);
    logits_kernel<<<dim3(Tt / 128, 8), 256, 0, stream>>>(xb, xl, gB, part);
    hipMemsetAsync(counts, 0, 64, stream);
    topk_kernel<<<Tt / 64, 64, 0, stream>>>(part, comb, selids, counts);
    offsets_kernel<<<1, 1, 0, stream>>>(counts, off, cursor, blocktab, meta);
    hipMemsetAsync(rowmap, 0xFF, MAXROWS * sizeof(int), stream);
    scatter_kernel<<<8, 256, 0, stream>>>(selids, off, cursor, rowmap, tokpos);
    gemm1_kernel<<<dim3(Ff / 64, MAXTILES), 256, 0, stream>>>(
        xb, Wg, sWg, Wu, sWu, comb, rowmap, blocktab, meta, Hp);
    gemm2_kernel<<<dim3(Dd / 128, MAXTILES), 256, 0, stream>>>(
        Hp, Wd, sWd, blocktab, meta, Op);
    reduce_kernel<<<Tt, 256, 0, stream>>>(Op, tokpos, out);
}